// Round 7
// baseline (682.900 us; speedup 1.0000x reference)
//
#include <hip/hip_runtime.h>
#include <hip/hip_fp16.h>

#define S_LEN 2048
#define DKV 64
#define NBH 32
#define CTX_ELEMS ((size_t)NBH * S_LEN * DKV)

using half8 = __attribute__((ext_vector_type(8))) _Float16;
using half4 = __attribute__((ext_vector_type(4))) _Float16;
using f32x4 = __attribute__((ext_vector_type(4))) float;
using u32x4 = __attribute__((ext_vector_type(4))) unsigned int;

#define MFMA16x32(a, b, c) __builtin_amdgcn_mfma_f32_16x16x32_f16((a), (b), (c), 0, 0, 0)

#if defined(__has_builtin)
#if __has_builtin(__builtin_amdgcn_mfma_f32_16x16x16f16)
#define MFMA16x16(a, b, c) __builtin_amdgcn_mfma_f32_16x16x16f16((a), (b), (c), 0, 0, 0)
#elif __has_builtin(__builtin_amdgcn_mfma_f32_16x16x16_f16)
#define MFMA16x16(a, b, c) __builtin_amdgcn_mfma_f32_16x16x16_f16((a), (b), (c), 0, 0, 0)
#endif
#endif
#ifndef MFMA16x16
#define MFMA16x16(a, b, c) __builtin_amdgcn_mfma_f32_16x16x16f16((a), (b), (c), 0, 0, 0)
#endif

// ---------------------------------------------------------------------------
// Runtime mask-dtype detection (1-byte bool vs 4-byte int/float 0/1).
// ---------------------------------------------------------------------------
__global__ void detect_mask_kernel(const unsigned char* __restrict__ mask,
                                   int* __restrict__ flag) {
  __shared__ int nz0s, nzos;
  if (threadIdx.x == 0) { nz0s = 0; nzos = 0; }
  __syncthreads();
  int nz0 = 0, nzo = 0;
  for (int i = threadIdx.x; i < 65536; i += 256) {
    unsigned char b = mask[i];
    if (b) { if ((i & 3) == 0) nz0++; else nzo++; }
  }
  atomicAdd(&nz0s, nz0);
  atomicAdd(&nzos, nzo);
  __syncthreads();
  if (threadIdx.x == 0) *flag = (nz0s > 0 && nzos > 0) ? 0 : 1;
}

// ---------------------------------------------------------------------------
// Pack mask -> 1 bit per element. Bit f of dword bits[f>>5] = (mask[f] != 0).
// ---------------------------------------------------------------------------
__global__ void pack_mask_kernel(const void* __restrict__ maskv,
                                 const int* __restrict__ flag,
                                 unsigned int* __restrict__ bits) {
  __shared__ unsigned char nib[256];
  const bool w4 = (*flag) != 0;
  const unsigned int* m32 = (const unsigned int*)maskv;
  const int tid = threadIdx.x;
  for (int it = 0; it < 64; ++it) {
    const size_t e0 = ((size_t)blockIdx.x * 64 + it) * 1024;  // element base
    const size_t ei = e0 + (size_t)tid * 4;
    unsigned int nv;
    if (w4) {
      u32x4 v = __builtin_nontemporal_load((const u32x4*)(m32 + ei));
      nv = (v[0] ? 1u : 0u) | (v[1] ? 2u : 0u) | (v[2] ? 4u : 0u) | (v[3] ? 8u : 0u);
    } else {
      unsigned int b = __builtin_nontemporal_load(m32 + (ei >> 2));
      nv = ((b & 0xffu) ? 1u : 0u) | ((b & 0xff00u) ? 2u : 0u) |
           ((b & 0xff0000u) ? 4u : 0u) | ((b & 0xff000000u) ? 8u : 0u);
    }
    __syncthreads();
    nib[tid] = (unsigned char)nv;
    __syncthreads();
    if (tid < 32) {
      unsigned int dw = 0;
#pragma unroll
      for (int t = 0; t < 8; ++t)
        dw |= ((unsigned int)nib[tid * 8 + t]) << (t * 4);
      bits[(e0 >> 5) + tid] = dw;
    }
  }
}

// ---------------------------------------------------------------------------
// fp32 -> fp16 elementwise (Q, K).
// ---------------------------------------------------------------------------
__global__ void convert_f32_f16_kernel(const float* __restrict__ src,
                                       _Float16* __restrict__ dst) {
  size_t i = (size_t)blockIdx.x * blockDim.x + threadIdx.x;
  f32x4 v = *(const f32x4*)(src + i * 4);
  half4 h;
#pragma unroll
  for (int j = 0; j < 4; j++) h[j] = (_Float16)v[j];
  *(half4*)(dst + i * 4) = h;
}

// ---------------------------------------------------------------------------
// V [bh][k][d] fp32 -> VT [bh][d][k] fp16.
// ---------------------------------------------------------------------------
__global__ void transpose_v_kernel(const float* __restrict__ V,
                                   _Float16* __restrict__ VT) {
  __shared__ _Float16 t[64][68];
  const int bh = blockIdx.y;
  const int k0 = blockIdx.x * 64;
  const float* Vb = V + ((size_t)bh * S_LEN + k0) * DKV;
#pragma unroll
  for (int it = 0; it < 4; it++) {
    int idx = threadIdx.x + it * 256;
    int kl = idx >> 4;
    int dq = (idx & 15) * 4;
    f32x4 v = *(const f32x4*)(Vb + (size_t)kl * DKV + dq);
#pragma unroll
    for (int j = 0; j < 4; j++) t[kl][dq + j] = (_Float16)v[j];
  }
  __syncthreads();
  _Float16* VTb = VT + (size_t)bh * DKV * S_LEN;
#pragma unroll
  for (int it = 0; it < 4; it++) {
    int idx = threadIdx.x + it * 256;
    int d = idx >> 4;
    int kq = (idx & 15) * 4;
    half4 h;
#pragma unroll
    for (int j = 0; j < 4; j++) h[j] = t[kq + j][d];
    *(half4*)(VTb + (size_t)d * S_LEN + k0 + kq) = h;
  }
}

// ---------------------------------------------------------------------------
// Main attention v5: swapped QK^T (S^T = K·Q^T) so P stays in registers as
// the PV 16x16x16 A-fragment; attn stores are register-direct f32x4 covering
// full 64B sectors. 512 thr (8 waves) = 4 q-tiles x 2 k-halves, no-max
// softmax. launch_bounds(512,3): VGPR cap 85, no spills (R5/R6 lesson:
// 2nd arg acts as blocks/CU; caps 32/40 VGPR caused massive scratch).
// ---------------------------------------------------------------------------
__global__ __launch_bounds__(512, 3)
void attn_v5_kernel(const _Float16* __restrict__ QH, const _Float16* __restrict__ KH,
                    const _Float16* __restrict__ VT, const unsigned int* __restrict__ bits,
                    float* __restrict__ out) {
  __shared__ float zbuf[4][2][16];
  __shared__ __align__(16) float cbuf[4][16][64];

  const int tid = threadIdx.x;
  const int w = tid >> 6;
  const int lane = tid & 63;
  const int g = lane >> 4;       // k-subrow group 0..3
  const int c = lane & 15;       // q column 0..15
  const int qt = w >> 1;         // q-tile within block
  const int half = w & 1;        // k-half: k in [half*1024, half*1024+1024)

  // XCD-chunked swizzle (1024 % 8 == 0 -> bijective).
  const int phys = blockIdx.x;
  const int orig = (phys & 7) * 128 + (phys >> 3);
  const int tile = orig * 4 + qt;          // 0..4095
  const int bh = tile >> 7;
  const int q0 = (tile & 127) << 4;

  // Q B-fragment: lane holds Q[q0+c][g*8+j] (and +32) -- same rows as before.
  const _Float16* qp = QH + ((size_t)(bh * S_LEN + q0 + c)) * DKV + g * 8;
  const half8 a0 = *(const half8*)qp;
  const half8 a1 = *(const half8*)(qp + 32);

  const _Float16* Kb = KH + (size_t)bh * S_LEN * DKV;
  const unsigned int* bq = bits + ((size_t)(bh * S_LEN + q0)) * (S_LEN / 32);

  // ---------------- pass 1: Z[q=c] = sum over unmasked exp(s) --------------
  float Zs = 0.0f;
  for (int ks = half * 32; ks < half * 32 + 32; ++ks) {
    const unsigned int bw = bq[(size_t)c * (S_LEN / 32) + ks];
#pragma unroll
    for (int t = 0; t < 2; ++t) {
      const int kt = ks * 2 + t;           // 16-k tile index
      // K A-fragment: lane holds K[kt*16 + c? no: row=l&15 -> k-index]
      const _Float16* kp = Kb + ((size_t)(kt * 16 + c)) * DKV + g * 8;
      half8 k00 = *(const half8*)kp;
      half8 k01 = *(const half8*)(kp + 32);
      f32x4 acc = (f32x4)0.0f;
      acc = MFMA16x32(k00, a0, acc);       // S^T[k][q] tile
      acc = MFMA16x32(k01, a1, acc);
      // lane l, reg e -> S[q = l&15][k = kt*16 + 4*(l>>4) + e]
      const int bbase = t * 16 + g * 4;
#pragma unroll
      for (int e = 0; e < 4; e++) {
        float p = ((bw >> (bbase + e)) & 1u) ? 0.0f : __expf(acc[e] * 0.125f);
        Zs += p;
      }
    }
  }
  // sum over the 4 g-groups sharing each q (lane bits 4,5)
  Zs += __shfl_xor(Zs, 16, 64);
  Zs += __shfl_xor(Zs, 32, 64);
  if (lane < 16) zbuf[qt][half][lane] = Zs;
  __syncthreads();
  const float lZ = __logf(zbuf[qt][0][c] + zbuf[qt][1][c]);

  // ---------------- pass 2: attn = exp(s - lnZ) (reg-direct store), PV -----
  f32x4 ctx[4];
#pragma unroll
  for (int nn = 0; nn < 4; nn++) ctx[nn] = (f32x4)0.0f;

  const _Float16* Vb = VT + (size_t)bh * DKV * S_LEN;
  float* attn_row = out + CTX_ELEMS + ((size_t)(bh * S_LEN + q0 + c)) * S_LEN;

  for (int ks = half * 32; ks < half * 32 + 32; ++ks) {
    const unsigned int bw = bq[(size_t)c * (S_LEN / 32) + ks];
#pragma unroll
    for (int t = 0; t < 2; ++t) {
      const int kt = ks * 2 + t;
      const _Float16* kp = Kb + ((size_t)(kt * 16 + c)) * DKV + g * 8;
      half8 k00 = *(const half8*)kp;
      half8 k01 = *(const half8*)(kp + 32);
      f32x4 acc = (f32x4)0.0f;
      acc = MFMA16x32(k00, a0, acc);
      acc = MFMA16x32(k01, a1, acc);
      const int bbase = t * 16 + g * 4;
      f32x4 p;
      half4 pa;
#pragma unroll
      for (int e = 0; e < 4; e++) {
        float v = ((bw >> (bbase + e)) & 1u) ? 0.0f : __expf(acc[e] * 0.125f - lZ);
        p[e] = v;
        pa[e] = (_Float16)v;
      }
      // attn store: lane writes attn[q0+c][kt*16 + 4g .. +3] -- 16 B/lane,
      // per inst: 16 rows x 64 B (full sectors).
      __builtin_nontemporal_store(p, (f32x4*)(attn_row + kt * 16 + g * 4));
      // PV: ctx[q][d] += P[q][k-tile] * V[k-tile][d], K=16 MFMA.
      // A-frag = pa (lane: row q=c, k=4g+e). B-frag from VT: lane holds
      // V[kt*16+4g+j][d=nn*16+c].
#pragma unroll
      for (int nn = 0; nn < 4; nn++) {
        half4 vb = *(const half4*)(Vb + (size_t)(nn * 16 + c) * S_LEN + kt * 16 + g * 4);
        ctx[nn] = MFMA16x16(pa, vb, ctx[nn]);
      }
    }
  }

  // ---------------- ctx combine across the two halves ----------------------
  // ctx layout: lane l, reg e -> ctx[q = 4*(l>>4)+e][d = nn*16 + (l&15)]
  __syncthreads();
  if (half == 1) {
#pragma unroll
    for (int nn = 0; nn < 4; nn++) {
#pragma unroll
      for (int e = 0; e < 4; e++)
        cbuf[qt][g * 4 + e][nn * 16 + c] = ctx[nn][e];
    }
  }
  __syncthreads();
  if (half == 0) {
    float* cb = out + ((size_t)(bh * S_LEN + q0)) * DKV;
#pragma unroll
    for (int nn = 0; nn < 4; nn++) {
#pragma unroll
      for (int e = 0; e < 4; e++) {
        float v = ctx[nn][e] + cbuf[qt][g * 4 + e][nn * 16 + c];
        __builtin_nontemporal_store(v, cb + (size_t)(g * 4 + e) * DKV + nn * 16 + c);
      }
    }
  }
}

// ---------------------------------------------------------------------------
// Fallback (R1 kernel) if ws is too small.
// ---------------------------------------------------------------------------
__global__ __launch_bounds__(512, 1)
void attn_slow_kernel(const float* __restrict__ Q, const float* __restrict__ K,
                      const float* __restrict__ V, const void* __restrict__ maskv,
                      float* __restrict__ out, const int* __restrict__ flag) {
  __shared__ __align__(16) unsigned char smem[16 * 2056 * 2];
  __shared__ float redm[8][16];
  __shared__ float reds[8][16];
  _Float16 (*P)[2056] = (_Float16 (*)[2056])smem;

  const int bh = blockIdx.y;
  const int q0 = blockIdx.x << 4;
  const int tid = threadIdx.x;
  const int w = tid >> 6;
  const int lane = tid & 63;
  const int g = lane >> 4;
  const int c = lane & 15;
  const int k0 = w << 8;

  const bool mask_w = (*flag) != 0;
  const unsigned char* m8 = (const unsigned char*)maskv;
  const unsigned int* m32 = (const unsigned int*)maskv;

  const float* Qb = Q + ((size_t)bh * S_LEN + q0) * DKV;
  const float* Kb = K + (size_t)bh * S_LEN * DKV;
  const float* Vb = V + (size_t)bh * S_LEN * DKV;
  const size_t mbase = ((size_t)bh * S_LEN + q0) * S_LEN;
  float* ctx_out = out + ((size_t)bh * S_LEN + q0) * DKV;
  float* attn_out = out + CTX_ELEMS + mbase;

  half8 a0, a1;
  {
    const float* qrow = Qb + (size_t)c * DKV + g * 8;
    f32x4 x0 = *(const f32x4*)(qrow);
    f32x4 x1 = *(const f32x4*)(qrow + 4);
    f32x4 y0 = *(const f32x4*)(qrow + 32);
    f32x4 y1 = *(const f32x4*)(qrow + 36);
#pragma unroll
    for (int j = 0; j < 4; j++) {
      a0[j] = (_Float16)x0[j]; a0[4 + j] = (_Float16)x1[j];
      a1[j] = (_Float16)y0[j]; a1[4 + j] = (_Float16)y1[j];
    }
  }

  f32x4 acc[16];
#pragma unroll
  for (int n = 0; n < 16; n++) acc[n] = (f32x4)0.0f;
#pragma unroll
  for (int n = 0; n < 16; n++) {
    const float* kr = Kb + (size_t)(k0 + n * 16 + c) * DKV + g * 8;
    f32x4 x0 = *(const f32x4*)(kr);
    f32x4 x1 = *(const f32x4*)(kr + 4);
    f32x4 y0 = *(const f32x4*)(kr + 32);
    f32x4 y1 = *(const f32x4*)(kr + 36);
    half8 b0, b1;
#pragma unroll
    for (int j = 0; j < 4; j++) {
      b0[j] = (_Float16)x0[j]; b0[4 + j] = (_Float16)x1[j];
      b1[j] = (_Float16)y0[j]; b1[4 + j] = (_Float16)y1[j];
    }
    acc[n] = MFMA16x32(a0, b0, acc[n]);
    acc[n] = MFMA16x32(a1, b1, acc[n]);
  }

  float mx[4] = {-1e9f, -1e9f, -1e9f, -1e9f};
#pragma unroll
  for (int n = 0; n < 16; n++) {
    const int kc = k0 + n * 16 + c;
#pragma unroll
    for (int e = 0; e < 4; e++) {
      const size_t mi = mbase + (size_t)(g * 4 + e) * S_LEN + kc;
      bool masked;
      if (mask_w) masked = (__builtin_nontemporal_load(&m32[mi]) != 0u);
      else        masked = (__builtin_nontemporal_load(&m8[mi]) != 0);
      float s = masked ? -1e9f : acc[n][e] * 0.125f;
      acc[n][e] = s;
      mx[e] = fmaxf(mx[e], s);
    }
  }
#pragma unroll
  for (int off = 1; off < 16; off <<= 1) {
#pragma unroll
    for (int e = 0; e < 4; e++)
      mx[e] = fmaxf(mx[e], __shfl_xor(mx[e], off, 64));
  }
  if (c == 0) {
#pragma unroll
    for (int e = 0; e < 4; e++) redm[w][g * 4 + e] = mx[e];
  }
  __syncthreads();
  float m[4], sm[4];
#pragma unroll
  for (int e = 0; e < 4; e++) {
    float v = redm[0][g * 4 + e];
#pragma unroll
    for (int ww = 1; ww < 8; ww++) v = fmaxf(v, redm[ww][g * 4 + e]);
    m[e] = v;
    sm[e] = 0.0f;
  }
#pragma unroll
  for (int n = 0; n < 16; n++) {
#pragma unroll
    for (int e = 0; e < 4; e++) {
      float p = __expf(acc[n][e] - m[e]);
      acc[n][e] = p;
      sm[e] += p;
    }
  }
#pragma unroll
  for (int off = 1; off < 16; off <<= 1) {
#pragma unroll
    for (int e = 0; e < 4; e++) sm[e] += __shfl_xor(sm[e], off, 64);
  }
  if (c == 0) {
#pragma unroll
    for (int e = 0; e < 4; e++) reds[w][g * 4 + e] = sm[e];
  }
  __syncthreads();
  float inv[4];
#pragma unroll
  for (int e = 0; e < 4; e++) {
    float z = 0.0f;
#pragma unroll
    for (int ww = 0; ww < 8; ww++) z += reds[ww][g * 4 + e];
    inv[e] = 1.0f / z;
  }
#pragma unroll
  for (int n = 0; n < 16; n++) {
    const int kc = k0 + n * 16 + c;
#pragma unroll
    for (int e = 0; e < 4; e++) {
      float v = acc[n][e] * inv[e];
      __builtin_nontemporal_store(v, &attn_out[(size_t)(g * 4 + e) * S_LEN + kc]);
      P[g * 4 + e][kc] = (_Float16)v;
    }
  }
  __syncthreads();

  f32x4 ctx[4];
#pragma unroll
  for (int n = 0; n < 4; n++) ctx[n] = (f32x4)0.0f;
  for (int ks = 0; ks < 8; ks++) {
    const int kb = k0 + ks * 32;
    half8 pa = *(const half8*)&P[c][kb + g * 8];
#pragma unroll
    for (int n = 0; n < 4; n++) {
      const float* vp = Vb + (size_t)(kb + g * 8) * DKV + n * 16 + c;
      half8 vb;
#pragma unroll
      for (int j = 0; j < 8; j++) vb[j] = (_Float16)vp[(size_t)j * DKV];
      ctx[n] = MFMA16x32(pa, vb, ctx[n]);
    }
  }
  __syncthreads();

  float* red2 = (float*)smem;
#pragma unroll
  for (int n = 0; n < 4; n++) {
#pragma unroll
    for (int e = 0; e < 4; e++)
      red2[((w * 16) + g * 4 + e) * 64 + n * 16 + c] = ctx[n][e];
  }
  __syncthreads();
  for (int i = tid; i < 16 * 64; i += 512) {
    int q = i >> 6, d = i & 63;
    float ssum = 0.0f;
#pragma unroll
    for (int ww = 0; ww < 8; ww++) ssum += red2[((ww * 16) + q) * 64 + d];
    ctx_out[(size_t)q * DKV + d] = ssum;
  }
}

extern "C" void kernel_launch(void* const* d_in, const int* in_sizes, int n_in,
                              void* d_out, int out_size, void* d_ws, size_t ws_size,
                              hipStream_t stream) {
  (void)in_sizes; (void)n_in; (void)out_size;
  const float* Q = (const float*)d_in[0];
  const float* K = (const float*)d_in[1];
  const float* V = (const float*)d_in[2];
  const void* mask = d_in[3];

  const size_t HBYTES = (size_t)NBH * S_LEN * DKV * sizeof(_Float16);       // 8 MB
  const size_t BITBYTES = (size_t)NBH * S_LEN * (S_LEN / 32) * 4;           // 16 MB
  const size_t NEED = 256 + 3 * HBYTES + BITBYTES;

  int* flag = (int*)d_ws;
  hipLaunchKernelGGL(detect_mask_kernel, dim3(1), dim3(256), 0, stream,
                     (const unsigned char*)mask, flag);

  if (ws_size >= NEED) {
    _Float16* QH = (_Float16*)((char*)d_ws + 256);
    _Float16* KH = (_Float16*)((char*)d_ws + 256 + HBYTES);
    _Float16* VT = (_Float16*)((char*)d_ws + 256 + 2 * HBYTES);
    unsigned int* bits = (unsigned int*)((char*)d_ws + 256 + 3 * HBYTES);
    const int n4 = NBH * S_LEN * DKV / 4;
    hipLaunchKernelGGL(pack_mask_kernel, dim3(2048), dim3(256), 0, stream,
                       mask, flag, bits);
    hipLaunchKernelGGL(convert_f32_f16_kernel, dim3(n4 / 256), dim3(256), 0, stream, Q, QH);
    hipLaunchKernelGGL(convert_f32_f16_kernel, dim3(n4 / 256), dim3(256), 0, stream, K, KH);
    hipLaunchKernelGGL(transpose_v_kernel, dim3(S_LEN / 64, NBH), dim3(256), 0, stream, V, VT);
    hipLaunchKernelGGL(attn_v5_kernel, dim3(1024), dim3(512), 0, stream,
                       QH, KH, VT, bits, (float*)d_out);
  } else {
    hipLaunchKernelGGL(attn_slow_kernel, dim3(128, 32), dim3(512), 0, stream,
                       Q, K, V, mask, (float*)d_out, flag);
  }
}

// Round 8
// 529.999 us; speedup vs baseline: 1.2885x; 1.2885x over previous
//
#include <hip/hip_runtime.h>
#include <hip/hip_fp16.h>

#define S_LEN 2048
#define DKV 64
#define NBH 32
#define CTX_ELEMS ((size_t)NBH * S_LEN * DKV)

using half8 = __attribute__((ext_vector_type(8))) _Float16;
using half4 = __attribute__((ext_vector_type(4))) _Float16;
using f32x4 = __attribute__((ext_vector_type(4))) float;
using u32x4 = __attribute__((ext_vector_type(4))) unsigned int;

#define MFMA16x32(a, b, c) __builtin_amdgcn_mfma_f32_16x16x32_f16((a), (b), (c), 0, 0, 0)

// ---------------------------------------------------------------------------
// Runtime mask-dtype detection (1-byte bool vs 4-byte int/float 0/1).
// ---------------------------------------------------------------------------
__global__ void detect_mask_kernel(const unsigned char* __restrict__ mask,
                                   int* __restrict__ flag) {
  __shared__ int nz0s, nzos;
  if (threadIdx.x == 0) { nz0s = 0; nzos = 0; }
  __syncthreads();
  int nz0 = 0, nzo = 0;
  for (int i = threadIdx.x; i < 65536; i += 256) {
    unsigned char b = mask[i];
    if (b) { if ((i & 3) == 0) nz0++; else nzo++; }
  }
  atomicAdd(&nz0s, nz0);
  atomicAdd(&nzos, nzo);
  __syncthreads();
  if (threadIdx.x == 0) *flag = (nz0s > 0 && nzos > 0) ? 0 : 1;
}

// ---------------------------------------------------------------------------
// Pack mask -> 1 bit per element. Bit f of dword bits[f>>5] = (mask[f] != 0).
// ---------------------------------------------------------------------------
__global__ void pack_mask_kernel(const void* __restrict__ maskv,
                                 const int* __restrict__ flag,
                                 unsigned int* __restrict__ bits) {
  __shared__ unsigned char nib[256];
  const bool w4 = (*flag) != 0;
  const unsigned int* m32 = (const unsigned int*)maskv;
  const int tid = threadIdx.x;
  for (int it = 0; it < 64; ++it) {
    const size_t e0 = ((size_t)blockIdx.x * 64 + it) * 1024;  // element base
    const size_t ei = e0 + (size_t)tid * 4;
    unsigned int nv;
    if (w4) {
      u32x4 v = __builtin_nontemporal_load((const u32x4*)(m32 + ei));
      nv = (v[0] ? 1u : 0u) | (v[1] ? 2u : 0u) | (v[2] ? 4u : 0u) | (v[3] ? 8u : 0u);
    } else {
      unsigned int b = __builtin_nontemporal_load(m32 + (ei >> 2));
      nv = ((b & 0xffu) ? 1u : 0u) | ((b & 0xff00u) ? 2u : 0u) |
           ((b & 0xff0000u) ? 4u : 0u) | ((b & 0xff000000u) ? 8u : 0u);
    }
    __syncthreads();
    nib[tid] = (unsigned char)nv;
    __syncthreads();
    if (tid < 32) {
      unsigned int dw = 0;
#pragma unroll
      for (int t = 0; t < 8; ++t)
        dw |= ((unsigned int)nib[tid * 8 + t]) << (t * 4);
      bits[(e0 >> 5) + tid] = dw;
    }
  }
}

// ---------------------------------------------------------------------------
// fp32 -> fp16 elementwise (Q, K).
// ---------------------------------------------------------------------------
__global__ void convert_f32_f16_kernel(const float* __restrict__ src,
                                       _Float16* __restrict__ dst) {
  size_t i = (size_t)blockIdx.x * blockDim.x + threadIdx.x;
  f32x4 v = *(const f32x4*)(src + i * 4);
  half4 h;
#pragma unroll
  for (int j = 0; j < 4; j++) h[j] = (_Float16)v[j];
  *(half4*)(dst + i * 4) = h;
}

// ---------------------------------------------------------------------------
// V [bh][k][d] fp32 -> VT [bh][d][k] fp16.
// ---------------------------------------------------------------------------
__global__ void transpose_v_kernel(const float* __restrict__ V,
                                   _Float16* __restrict__ VT) {
  __shared__ _Float16 t[64][68];
  const int bh = blockIdx.y;
  const int k0 = blockIdx.x * 64;
  const float* Vb = V + ((size_t)bh * S_LEN + k0) * DKV;
#pragma unroll
  for (int it = 0; it < 4; it++) {
    int idx = threadIdx.x + it * 256;
    int kl = idx >> 4;
    int dq = (idx & 15) * 4;
    f32x4 v = *(const f32x4*)(Vb + (size_t)kl * DKV + dq);
#pragma unroll
    for (int j = 0; j < 4; j++) t[kl][dq + j] = (_Float16)v[j];
  }
  __syncthreads();
  _Float16* VTb = VT + (size_t)bh * DKV * S_LEN;
#pragma unroll
  for (int it = 0; it < 4; it++) {
    int idx = threadIdx.x + it * 256;
    int d = idx >> 4;
    int kq = (idx & 15) * 4;
    half4 h;
#pragma unroll
    for (int j = 0; j < 4; j++) h[j] = t[kq + j][d];
    *(half4*)(VTb + (size_t)d * S_LEN + k0 + kq) = h;
  }
}

// ---------------------------------------------------------------------------
// Main attention v6 (= v4 structure, fixed register budget):
// 512 thr (8 waves) = 4 q-tiles x 2 k-halves; no-max softmax.
// launch_bounds(512,4): VGPR cap 64 (R2 precedent: compiles to 64, no
// spill catastrophe). K-frag loads staggered to keep peak live regs <= cap.
// ---------------------------------------------------------------------------
__global__ __launch_bounds__(512, 4)
void attn_v6_kernel(const _Float16* __restrict__ QH, const _Float16* __restrict__ KH,
                    const _Float16* __restrict__ VT, const unsigned int* __restrict__ bits,
                    float* __restrict__ out) {
  __shared__ __align__(16) _Float16 pbuf[8][16][40];  // per-wave P slice
  __shared__ float zbuf[4][2][16];
  __shared__ __align__(16) float cbuf[4][16][64];

  const int tid = threadIdx.x;
  const int w = tid >> 6;
  const int lane = tid & 63;
  const int g = lane >> 4;
  const int c = lane & 15;
  const int qt = w >> 1;         // q-tile within block
  const int half = w & 1;        // k-half: kt4 in [half*8, half*8+8)

  // XCD-chunked swizzle (1024 % 8 == 0 -> bijective).
  const int phys = blockIdx.x;
  const int orig = (phys & 7) * 128 + (phys >> 3);
  const int tile = orig * 4 + qt;          // 0..4095
  const int bh = tile >> 7;
  const int q0 = (tile & 127) << 4;

  const _Float16* qp = QH + ((size_t)(bh * S_LEN + q0 + c)) * DKV + g * 8;
  const half8 a0 = *(const half8*)qp;
  const half8 a1 = *(const half8*)(qp + 32);

  const _Float16* Kb = KH + (size_t)bh * S_LEN * DKV;
  const unsigned int* bq = bits + ((size_t)(bh * S_LEN + q0)) * (S_LEN / 32);

  float Zs[4] = {0.0f, 0.0f, 0.0f, 0.0f};

  // ---------------- pass 1: Z = sum over unmasked exp(s) -------------------
  for (int kt4 = half * 8; kt4 < half * 8 + 8; ++kt4) {
#pragma unroll
    for (int sub = 0; sub < 4; ++sub) {
      const int kt = kt4 * 4 + sub;
      unsigned int mw[4];
#pragma unroll
      for (int e = 0; e < 4; e++)
        mw[e] = bq[(size_t)(g * 4 + e) * (S_LEN / 32) + kt];
      const _Float16* kp = Kb + ((size_t)(kt * 32 + c)) * DKV + g * 8;
      f32x4 acc0 = (f32x4)0.0f, acc1 = (f32x4)0.0f;
      {
        half8 k00 = *(const half8*)kp;
        half8 k01 = *(const half8*)(kp + 32);
        acc0 = MFMA16x32(a0, k00, acc0);
        acc0 = MFMA16x32(a1, k01, acc0);
      }
      {
        half8 k10 = *(const half8*)(kp + 16 * DKV);
        half8 k11 = *(const half8*)(kp + 16 * DKV + 32);
        acc1 = MFMA16x32(a0, k10, acc1);
        acc1 = MFMA16x32(a1, k11, acc1);
      }
#pragma unroll
      for (int e = 0; e < 4; e++) {
        const unsigned int bw = mw[e];
        float p0 = ((bw >> c) & 1u) ? 0.0f : __expf(acc0[e] * 0.125f);
        float p1 = ((bw >> (16 + c)) & 1u) ? 0.0f : __expf(acc1[e] * 0.125f);
        Zs[e] += p0 + p1;
      }
    }
  }
  // merge the 16 c-lanes sharing each row
#pragma unroll
  for (int off = 1; off < 16; off <<= 1) {
#pragma unroll
    for (int e = 0; e < 4; e++) Zs[e] += __shfl_xor(Zs[e], off, 64);
  }
  if (c == 0) {
#pragma unroll
    for (int e = 0; e < 4; e++) zbuf[qt][half][g * 4 + e] = Zs[e];
  }
  __syncthreads();
  float lZ[4];
#pragma unroll
  for (int e = 0; e < 4; e++)
    lZ[e] = __logf(zbuf[qt][0][g * 4 + e] + zbuf[qt][1][g * 4 + e]);

  // ---------------- pass 2: attn = exp(s - lnZ), PV ------------------------
  f32x4 ctx[4];
#pragma unroll
  for (int nn = 0; nn < 4; nn++) ctx[nn] = (f32x4)0.0f;

  const _Float16* Vb = VT + (size_t)bh * DKV * S_LEN;
  float* attn_base = out + CTX_ELEMS + ((size_t)(bh * S_LEN + q0)) * S_LEN;

  for (int kt4 = half * 8; kt4 < half * 8 + 8; ++kt4) {
#pragma unroll
    for (int sub = 0; sub < 4; ++sub) {
      const int kt = kt4 * 4 + sub;
      unsigned int mw[4];
#pragma unroll
      for (int e = 0; e < 4; e++)
        mw[e] = bq[(size_t)(g * 4 + e) * (S_LEN / 32) + kt];
      const _Float16* kp = Kb + ((size_t)(kt * 32 + c)) * DKV + g * 8;
      f32x4 acc0 = (f32x4)0.0f, acc1 = (f32x4)0.0f;
      {
        half8 k00 = *(const half8*)kp;
        half8 k01 = *(const half8*)(kp + 32);
        acc0 = MFMA16x32(a0, k00, acc0);
        acc0 = MFMA16x32(a1, k01, acc0);
      }
      {
        half8 k10 = *(const half8*)(kp + 16 * DKV);
        half8 k11 = *(const half8*)(kp + 16 * DKV + 32);
        acc1 = MFMA16x32(a0, k10, acc1);
        acc1 = MFMA16x32(a1, k11, acc1);
      }
#pragma unroll
      for (int e = 0; e < 4; e++) {
        const unsigned int bw = mw[e];
        float p0 = ((bw >> c) & 1u) ? 0.0f : __expf(acc0[e] * 0.125f - lZ[e]);
        float p1 = ((bw >> (16 + c)) & 1u) ? 0.0f : __expf(acc1[e] * 0.125f - lZ[e]);
        pbuf[w][g * 4 + e][c] = (_Float16)p0;
        pbuf[w][g * 4 + e][16 + c] = (_Float16)p1;
      }
      // wave-synchronous LDS (same wave wrote, same wave reads)
      half8 pa = *(const half8*)&pbuf[w][c][g * 8];

      // attn stores: 2 instructions x 1 KB contiguous (8 rows x 128 B)
#pragma unroll
      for (int s = 0; s < 2; s++) {
        const int r = (lane >> 3) + s * 8;
        const int c4 = (lane & 7) * 4;
        half4 h = *(const half4*)&pbuf[w][r][c4];
        f32x4 o;
#pragma unroll
        for (int j = 0; j < 4; j++) o[j] = (float)h[j];
        __builtin_nontemporal_store(o,
            (f32x4*)(attn_base + (size_t)r * S_LEN + kt * 32 + c4));
      }
      // PV
#pragma unroll
      for (int nn = 0; nn < 4; nn++) {
        const _Float16* vp = Vb + (size_t)(nn * 16 + c) * S_LEN + kt * 32 + g * 8;
        half8 vb = *(const half8*)vp;
        ctx[nn] = MFMA16x32(pa, vb, ctx[nn]);
      }
    }
  }

  // ---------------- ctx combine across the two halves ----------------------
  __syncthreads();
  if (half == 1) {
#pragma unroll
    for (int nn = 0; nn < 4; nn++) {
#pragma unroll
      for (int e = 0; e < 4; e++)
        cbuf[qt][g * 4 + e][nn * 16 + c] = ctx[nn][e];
    }
  }
  __syncthreads();
  if (half == 0) {
    float* cb = out + ((size_t)(bh * S_LEN + q0)) * DKV;
#pragma unroll
    for (int nn = 0; nn < 4; nn++) {
#pragma unroll
      for (int e = 0; e < 4; e++) {
        float v = ctx[nn][e] + cbuf[qt][g * 4 + e][nn * 16 + c];
        __builtin_nontemporal_store(v, cb + (size_t)(g * 4 + e) * DKV + nn * 16 + c);
      }
    }
  }
}

// ---------------------------------------------------------------------------
// Fallback (R1 kernel) if ws is too small.
// ---------------------------------------------------------------------------
__global__ __launch_bounds__(512, 1)
void attn_slow_kernel(const float* __restrict__ Q, const float* __restrict__ K,
                      const float* __restrict__ V, const void* __restrict__ maskv,
                      float* __restrict__ out, const int* __restrict__ flag) {
  __shared__ __align__(16) unsigned char smem[16 * 2056 * 2];
  __shared__ float redm[8][16];
  __shared__ float reds[8][16];
  _Float16 (*P)[2056] = (_Float16 (*)[2056])smem;

  const int bh = blockIdx.y;
  const int q0 = blockIdx.x << 4;
  const int tid = threadIdx.x;
  const int w = tid >> 6;
  const int lane = tid & 63;
  const int g = lane >> 4;
  const int c = lane & 15;
  const int k0 = w << 8;

  const bool mask_w = (*flag) != 0;
  const unsigned char* m8 = (const unsigned char*)maskv;
  const unsigned int* m32 = (const unsigned int*)maskv;

  const float* Qb = Q + ((size_t)bh * S_LEN + q0) * DKV;
  const float* Kb = K + (size_t)bh * S_LEN * DKV;
  const float* Vb = V + (size_t)bh * S_LEN * DKV;
  const size_t mbase = ((size_t)bh * S_LEN + q0) * S_LEN;
  float* ctx_out = out + ((size_t)bh * S_LEN + q0) * DKV;
  float* attn_out = out + CTX_ELEMS + mbase;

  half8 a0, a1;
  {
    const float* qrow = Qb + (size_t)c * DKV + g * 8;
    f32x4 x0 = *(const f32x4*)(qrow);
    f32x4 x1 = *(const f32x4*)(qrow + 4);
    f32x4 y0 = *(const f32x4*)(qrow + 32);
    f32x4 y1 = *(const f32x4*)(qrow + 36);
#pragma unroll
    for (int j = 0; j < 4; j++) {
      a0[j] = (_Float16)x0[j]; a0[4 + j] = (_Float16)x1[j];
      a1[j] = (_Float16)y0[j]; a1[4 + j] = (_Float16)y1[j];
    }
  }

  f32x4 acc[16];
#pragma unroll
  for (int n = 0; n < 16; n++) acc[n] = (f32x4)0.0f;
#pragma unroll
  for (int n = 0; n < 16; n++) {
    const float* kr = Kb + (size_t)(k0 + n * 16 + c) * DKV + g * 8;
    f32x4 x0 = *(const f32x4*)(kr);
    f32x4 x1 = *(const f32x4*)(kr + 4);
    f32x4 y0 = *(const f32x4*)(kr + 32);
    f32x4 y1 = *(const f32x4*)(kr + 36);
    half8 b0, b1;
#pragma unroll
    for (int j = 0; j < 4; j++) {
      b0[j] = (_Float16)x0[j]; b0[4 + j] = (_Float16)x1[j];
      b1[j] = (_Float16)y0[j]; b1[4 + j] = (_Float16)y1[j];
    }
    acc[n] = MFMA16x32(a0, b0, acc[n]);
    acc[n] = MFMA16x32(a1, b1, acc[n]);
  }

  float mx[4] = {-1e9f, -1e9f, -1e9f, -1e9f};
#pragma unroll
  for (int n = 0; n < 16; n++) {
    const int kc = k0 + n * 16 + c;
#pragma unroll
    for (int e = 0; e < 4; e++) {
      const size_t mi = mbase + (size_t)(g * 4 + e) * S_LEN + kc;
      bool masked;
      if (mask_w) masked = (__builtin_nontemporal_load(&m32[mi]) != 0u);
      else        masked = (__builtin_nontemporal_load(&m8[mi]) != 0);
      float s = masked ? -1e9f : acc[n][e] * 0.125f;
      acc[n][e] = s;
      mx[e] = fmaxf(mx[e], s);
    }
  }
#pragma unroll
  for (int off = 1; off < 16; off <<= 1) {
#pragma unroll
    for (int e = 0; e < 4; e++)
      mx[e] = fmaxf(mx[e], __shfl_xor(mx[e], off, 64));
  }
  if (c == 0) {
#pragma unroll
    for (int e = 0; e < 4; e++) redm[w][g * 4 + e] = mx[e];
  }
  __syncthreads();
  float m[4], sm[4];
#pragma unroll
  for (int e = 0; e < 4; e++) {
    float v = redm[0][g * 4 + e];
#pragma unroll
    for (int ww = 1; ww < 8; ww++) v = fmaxf(v, redm[ww][g * 4 + e]);
    m[e] = v;
    sm[e] = 0.0f;
  }
#pragma unroll
  for (int n = 0; n < 16; n++) {
#pragma unroll
    for (int e = 0; e < 4; e++) {
      float p = __expf(acc[n][e] - m[e]);
      acc[n][e] = p;
      sm[e] += p;
    }
  }
#pragma unroll
  for (int off = 1; off < 16; off <<= 1) {
#pragma unroll
    for (int e = 0; e < 4; e++) sm[e] += __shfl_xor(sm[e], off, 64);
  }
  if (c == 0) {
#pragma unroll
    for (int e = 0; e < 4; e++) reds[w][g * 4 + e] = sm[e];
  }
  __syncthreads();
  float inv[4];
#pragma unroll
  for (int e = 0; e < 4; e++) {
    float z = 0.0f;
#pragma unroll
    for (int ww = 0; ww < 8; ww++) z += reds[ww][g * 4 + e];
    inv[e] = 1.0f / z;
  }
#pragma unroll
  for (int n = 0; n < 16; n++) {
    const int kc = k0 + n * 16 + c;
#pragma unroll
    for (int e = 0; e < 4; e++) {
      float v = acc[n][e] * inv[e];
      __builtin_nontemporal_store(v, &attn_out[(size_t)(g * 4 + e) * S_LEN + kc]);
      P[g * 4 + e][kc] = (_Float16)v;
    }
  }
  __syncthreads();

  f32x4 ctx[4];
#pragma unroll
  for (int n = 0; n < 4; n++) ctx[n] = (f32x4)0.0f;
  for (int ks = 0; ks < 8; ks++) {
    const int kb = k0 + ks * 32;
    half8 pa = *(const half8*)&P[c][kb + g * 8];
#pragma unroll
    for (int n = 0; n < 4; n++) {
      const float* vp = Vb + (size_t)(kb + g * 8) * DKV + n * 16 + c;
      half8 vb;
#pragma unroll
      for (int j = 0; j < 8; j++) vb[j] = (_Float16)vp[(size_t)j * DKV];
      ctx[n] = MFMA16x32(pa, vb, ctx[n]);
    }
  }
  __syncthreads();

  float* red2 = (float*)smem;
#pragma unroll
  for (int n = 0; n < 4; n++) {
#pragma unroll
    for (int e = 0; e < 4; e++)
      red2[((w * 16) + g * 4 + e) * 64 + n * 16 + c] = ctx[n][e];
  }
  __syncthreads();
  for (int i = tid; i < 16 * 64; i += 512) {
    int q = i >> 6, d = i & 63;
    float ssum = 0.0f;
#pragma unroll
    for (int ww = 0; ww < 8; ww++) ssum += red2[((ww * 16) + q) * 64 + d];
    ctx_out[(size_t)q * DKV + d] = ssum;
  }
}

extern "C" void kernel_launch(void* const* d_in, const int* in_sizes, int n_in,
                              void* d_out, int out_size, void* d_ws, size_t ws_size,
                              hipStream_t stream) {
  (void)in_sizes; (void)n_in; (void)out_size;
  const float* Q = (const float*)d_in[0];
  const float* K = (const float*)d_in[1];
  const float* V = (const float*)d_in[2];
  const void* mask = d_in[3];

  const size_t HBYTES = (size_t)NBH * S_LEN * DKV * sizeof(_Float16);       // 8 MB
  const size_t BITBYTES = (size_t)NBH * S_LEN * (S_LEN / 32) * 4;           // 16 MB
  const size_t NEED = 256 + 3 * HBYTES + BITBYTES;

  int* flag = (int*)d_ws;
  hipLaunchKernelGGL(detect_mask_kernel, dim3(1), dim3(256), 0, stream,
                     (const unsigned char*)mask, flag);

  if (ws_size >= NEED) {
    _Float16* QH = (_Float16*)((char*)d_ws + 256);
    _Float16* KH = (_Float16*)((char*)d_ws + 256 + HBYTES);
    _Float16* VT = (_Float16*)((char*)d_ws + 256 + 2 * HBYTES);
    unsigned int* bits = (unsigned int*)((char*)d_ws + 256 + 3 * HBYTES);
    const int n4 = NBH * S_LEN * DKV / 4;
    hipLaunchKernelGGL(pack_mask_kernel, dim3(2048), dim3(256), 0, stream,
                       mask, flag, bits);
    hipLaunchKernelGGL(convert_f32_f16_kernel, dim3(n4 / 256), dim3(256), 0, stream, Q, QH);
    hipLaunchKernelGGL(convert_f32_f16_kernel, dim3(n4 / 256), dim3(256), 0, stream, K, KH);
    hipLaunchKernelGGL(transpose_v_kernel, dim3(S_LEN / 64, NBH), dim3(256), 0, stream, V, VT);
    hipLaunchKernelGGL(attn_v6_kernel, dim3(1024), dim3(512), 0, stream,
                       QH, KH, VT, bits, (float*)d_out);
  } else {
    hipLaunchKernelGGL(attn_slow_kernel, dim3(128, 32), dim3(512), 0, stream,
                       Q, K, V, mask, (float*)d_out, flag);
  }
}

// Round 9
// 385.722 us; speedup vs baseline: 1.7704x; 1.3740x over previous
//
#include <hip/hip_runtime.h>
#include <hip/hip_fp16.h>

#define S_LEN 2048
#define DKV 64
#define NBH 32
#define CTX_ELEMS ((size_t)NBH * S_LEN * DKV)

using half8 = __attribute__((ext_vector_type(8))) _Float16;
using half4 = __attribute__((ext_vector_type(4))) _Float16;
using f32x4 = __attribute__((ext_vector_type(4))) float;
using u32x4 = __attribute__((ext_vector_type(4))) unsigned int;

#define MFMA16x32(a, b, c) __builtin_amdgcn_mfma_f32_16x16x32_f16((a), (b), (c), 0, 0, 0)

// ---------------------------------------------------------------------------
// Runtime mask-dtype detection (1-byte bool vs 4-byte int/float 0/1).
// ---------------------------------------------------------------------------
__global__ void detect_mask_kernel(const unsigned char* __restrict__ mask,
                                   int* __restrict__ flag) {
  __shared__ int nz0s, nzos;
  if (threadIdx.x == 0) { nz0s = 0; nzos = 0; }
  __syncthreads();
  int nz0 = 0, nzo = 0;
  for (int i = threadIdx.x; i < 65536; i += 256) {
    unsigned char b = mask[i];
    if (b) { if ((i & 3) == 0) nz0++; else nzo++; }
  }
  atomicAdd(&nz0s, nz0);
  atomicAdd(&nzos, nzo);
  __syncthreads();
  if (threadIdx.x == 0) *flag = (nz0s > 0 && nzos > 0) ? 0 : 1;
}

// ---------------------------------------------------------------------------
// Pack mask -> 1 bit per element. Bit f of dword bits[f>>5] = (mask[f] != 0).
// ---------------------------------------------------------------------------
__global__ void pack_mask_kernel(const void* __restrict__ maskv,
                                 const int* __restrict__ flag,
                                 unsigned int* __restrict__ bits) {
  __shared__ unsigned char nib[256];
  const bool w4 = (*flag) != 0;
  const unsigned int* m32 = (const unsigned int*)maskv;
  const int tid = threadIdx.x;
  for (int it = 0; it < 64; ++it) {
    const size_t e0 = ((size_t)blockIdx.x * 64 + it) * 1024;  // element base
    const size_t ei = e0 + (size_t)tid * 4;
    unsigned int nv;
    if (w4) {
      u32x4 v = __builtin_nontemporal_load((const u32x4*)(m32 + ei));
      nv = (v[0] ? 1u : 0u) | (v[1] ? 2u : 0u) | (v[2] ? 4u : 0u) | (v[3] ? 8u : 0u);
    } else {
      unsigned int b = __builtin_nontemporal_load(m32 + (ei >> 2));
      nv = ((b & 0xffu) ? 1u : 0u) | ((b & 0xff00u) ? 2u : 0u) |
           ((b & 0xff0000u) ? 4u : 0u) | ((b & 0xff000000u) ? 8u : 0u);
    }
    __syncthreads();
    nib[tid] = (unsigned char)nv;
    __syncthreads();
    if (tid < 32) {
      unsigned int dw = 0;
#pragma unroll
      for (int t = 0; t < 8; ++t)
        dw |= ((unsigned int)nib[tid * 8 + t]) << (t * 4);
      bits[(e0 >> 5) + tid] = dw;
    }
  }
}

// ---------------------------------------------------------------------------
// fp32 -> fp16 elementwise (Q, K).
// ---------------------------------------------------------------------------
__global__ void convert_f32_f16_kernel(const float* __restrict__ src,
                                       _Float16* __restrict__ dst) {
  size_t i = (size_t)blockIdx.x * blockDim.x + threadIdx.x;
  f32x4 v = *(const f32x4*)(src + i * 4);
  half4 h;
#pragma unroll
  for (int j = 0; j < 4; j++) h[j] = (_Float16)v[j];
  *(half4*)(dst + i * 4) = h;
}

// ---------------------------------------------------------------------------
// V [bh][k][d] fp32 -> VT [bh][d][k] fp16.
// ---------------------------------------------------------------------------
__global__ void transpose_v_kernel(const float* __restrict__ V,
                                   _Float16* __restrict__ VT) {
  __shared__ _Float16 t[64][68];
  const int bh = blockIdx.y;
  const int k0 = blockIdx.x * 64;
  const float* Vb = V + ((size_t)bh * S_LEN + k0) * DKV;
#pragma unroll
  for (int it = 0; it < 4; it++) {
    int idx = threadIdx.x + it * 256;
    int kl = idx >> 4;
    int dq = (idx & 15) * 4;
    f32x4 v = *(const f32x4*)(Vb + (size_t)kl * DKV + dq);
#pragma unroll
    for (int j = 0; j < 4; j++) t[kl][dq + j] = (_Float16)v[j];
  }
  __syncthreads();
  _Float16* VTb = VT + (size_t)bh * DKV * S_LEN;
#pragma unroll
  for (int it = 0; it < 4; it++) {
    int idx = threadIdx.x + it * 256;
    int d = idx >> 4;
    int kq = (idx & 15) * 4;
    half4 h;
#pragma unroll
    for (int j = 0; j < 4; j++) h[j] = t[kq + j][d];
    *(half4*)(VTb + (size_t)d * S_LEN + k0 + kq) = h;
  }
}

// ---------------------------------------------------------------------------
// Main attention v7: each wave owns a 32-row q-tile (2 MFMA row-tiles A,B
// sharing K and V fragments -> halves L2 traffic, doubles per-load work).
// 512 thr (8 waves) = 4 q32-tiles x 2 k-halves; no-max softmax.
// launch_bounds arg2 = min BLOCKS/CU on this compiler (R5-R8 regression):
// (512,2) -> 16 waves/CU -> VGPR cap 128 (natural ~116, no spill).
// ---------------------------------------------------------------------------
__global__ __launch_bounds__(512, 2)
void attn_v7_kernel(const _Float16* __restrict__ QH, const _Float16* __restrict__ KH,
                    const _Float16* __restrict__ VT, const unsigned int* __restrict__ bits,
                    float* __restrict__ out) {
  __shared__ __align__(16) _Float16 pbuf[8][32][40];  // per-wave P slice [32 q][32 k]
  __shared__ float zbuf[4][2][32];
  __shared__ __align__(16) float cbuf[4][32][64];

  const int tid = threadIdx.x;
  const int w = tid >> 6;
  const int lane = tid & 63;
  const int g = lane >> 4;
  const int c = lane & 15;
  const int tb = w >> 1;         // q32-tile within block (0..3)
  const int half = w & 1;        // k-half: kt4 in [half*8, half*8+8)

  // XCD-chunked swizzle (512 % 8 == 0 -> bijective).
  const int phys = blockIdx.x;
  const int orig = (phys & 7) * 64 + (phys >> 3);
  const int tile = orig * 4 + tb;          // 0..2047 (q32 tiles)
  const int bh = tile >> 6;
  const int q0 = (tile & 63) << 5;

  // Q fragments for row-tiles A (q0..q0+15) and B (q0+16..q0+31)
  const _Float16* qpA = QH + ((size_t)(bh * S_LEN + q0 + c)) * DKV + g * 8;
  const half8 aA0 = *(const half8*)qpA;
  const half8 aA1 = *(const half8*)(qpA + 32);
  const _Float16* qpB = qpA + 16 * DKV;
  const half8 aB0 = *(const half8*)qpB;
  const half8 aB1 = *(const half8*)(qpB + 32);

  const _Float16* Kb = KH + (size_t)bh * S_LEN * DKV;
  const unsigned int* bq = bits + ((size_t)(bh * S_LEN + q0)) * (S_LEN / 32);

  float ZsA[4] = {0.0f, 0.0f, 0.0f, 0.0f};
  float ZsB[4] = {0.0f, 0.0f, 0.0f, 0.0f};

  // ---------------- pass 1: Z = sum over unmasked exp(s) -------------------
  for (int kt4 = half * 8; kt4 < half * 8 + 8; ++kt4) {
#pragma unroll
    for (int sub = 0; sub < 4; ++sub) {
      const int kt = kt4 * 4 + sub;
      unsigned int mwA[4], mwB[4];
#pragma unroll
      for (int e = 0; e < 4; e++) {
        mwA[e] = bq[(size_t)(g * 4 + e) * (S_LEN / 32) + kt];
        mwB[e] = bq[(size_t)(16 + g * 4 + e) * (S_LEN / 32) + kt];
      }
      const _Float16* kp = Kb + ((size_t)(kt * 32 + c)) * DKV + g * 8;
      half8 k00 = *(const half8*)kp;
      half8 k01 = *(const half8*)(kp + 32);
      half8 k10 = *(const half8*)(kp + 16 * DKV);
      half8 k11 = *(const half8*)(kp + 16 * DKV + 32);
      f32x4 acA0 = (f32x4)0.0f, acA1 = (f32x4)0.0f;
      f32x4 acB0 = (f32x4)0.0f, acB1 = (f32x4)0.0f;
      acA0 = MFMA16x32(aA0, k00, acA0);
      acA0 = MFMA16x32(aA1, k01, acA0);
      acB0 = MFMA16x32(aB0, k00, acB0);
      acB0 = MFMA16x32(aB1, k01, acB0);
      acA1 = MFMA16x32(aA0, k10, acA1);
      acA1 = MFMA16x32(aA1, k11, acA1);
      acB1 = MFMA16x32(aB0, k10, acB1);
      acB1 = MFMA16x32(aB1, k11, acB1);
#pragma unroll
      for (int e = 0; e < 4; e++) {
        float pA0 = ((mwA[e] >> c) & 1u) ? 0.0f : __expf(acA0[e] * 0.125f);
        float pA1 = ((mwA[e] >> (16 + c)) & 1u) ? 0.0f : __expf(acA1[e] * 0.125f);
        float pB0 = ((mwB[e] >> c) & 1u) ? 0.0f : __expf(acB0[e] * 0.125f);
        float pB1 = ((mwB[e] >> (16 + c)) & 1u) ? 0.0f : __expf(acB1[e] * 0.125f);
        ZsA[e] += pA0 + pA1;
        ZsB[e] += pB0 + pB1;
      }
    }
  }
  // merge the 16 c-lanes sharing each row
#pragma unroll
  for (int off = 1; off < 16; off <<= 1) {
#pragma unroll
    for (int e = 0; e < 4; e++) {
      ZsA[e] += __shfl_xor(ZsA[e], off, 64);
      ZsB[e] += __shfl_xor(ZsB[e], off, 64);
    }
  }
  if (c == 0) {
#pragma unroll
    for (int e = 0; e < 4; e++) {
      zbuf[tb][half][g * 4 + e] = ZsA[e];
      zbuf[tb][half][16 + g * 4 + e] = ZsB[e];
    }
  }
  __syncthreads();
  float lZA[4], lZB[4];
#pragma unroll
  for (int e = 0; e < 4; e++) {
    lZA[e] = __logf(zbuf[tb][0][g * 4 + e] + zbuf[tb][1][g * 4 + e]);
    lZB[e] = __logf(zbuf[tb][0][16 + g * 4 + e] + zbuf[tb][1][16 + g * 4 + e]);
  }

  // ---------------- pass 2: attn = exp(s - lnZ), PV ------------------------
  f32x4 ctxA[4], ctxB[4];
#pragma unroll
  for (int nn = 0; nn < 4; nn++) { ctxA[nn] = (f32x4)0.0f; ctxB[nn] = (f32x4)0.0f; }

  const _Float16* Vb = VT + (size_t)bh * DKV * S_LEN;
  float* attn_base = out + CTX_ELEMS + ((size_t)(bh * S_LEN + q0)) * S_LEN;

  for (int kt4 = half * 8; kt4 < half * 8 + 8; ++kt4) {
#pragma unroll
    for (int sub = 0; sub < 4; ++sub) {
      const int kt = kt4 * 4 + sub;
      unsigned int mwA[4], mwB[4];
#pragma unroll
      for (int e = 0; e < 4; e++) {
        mwA[e] = bq[(size_t)(g * 4 + e) * (S_LEN / 32) + kt];
        mwB[e] = bq[(size_t)(16 + g * 4 + e) * (S_LEN / 32) + kt];
      }
      const _Float16* kp = Kb + ((size_t)(kt * 32 + c)) * DKV + g * 8;
      half8 k00 = *(const half8*)kp;
      half8 k01 = *(const half8*)(kp + 32);
      half8 k10 = *(const half8*)(kp + 16 * DKV);
      half8 k11 = *(const half8*)(kp + 16 * DKV + 32);
      f32x4 acA0 = (f32x4)0.0f, acA1 = (f32x4)0.0f;
      f32x4 acB0 = (f32x4)0.0f, acB1 = (f32x4)0.0f;
      acA0 = MFMA16x32(aA0, k00, acA0);
      acA0 = MFMA16x32(aA1, k01, acA0);
      acB0 = MFMA16x32(aB0, k00, acB0);
      acB0 = MFMA16x32(aB1, k01, acB0);
      acA1 = MFMA16x32(aA0, k10, acA1);
      acA1 = MFMA16x32(aA1, k11, acA1);
      acB1 = MFMA16x32(aB0, k10, acB1);
      acB1 = MFMA16x32(aB1, k11, acB1);
#pragma unroll
      for (int e = 0; e < 4; e++) {
        float pA0 = ((mwA[e] >> c) & 1u) ? 0.0f : __expf(acA0[e] * 0.125f - lZA[e]);
        float pA1 = ((mwA[e] >> (16 + c)) & 1u) ? 0.0f : __expf(acA1[e] * 0.125f - lZA[e]);
        float pB0 = ((mwB[e] >> c) & 1u) ? 0.0f : __expf(acB0[e] * 0.125f - lZB[e]);
        float pB1 = ((mwB[e] >> (16 + c)) & 1u) ? 0.0f : __expf(acB1[e] * 0.125f - lZB[e]);
        pbuf[w][g * 4 + e][c] = (_Float16)pA0;
        pbuf[w][g * 4 + e][16 + c] = (_Float16)pA1;
        pbuf[w][16 + g * 4 + e][c] = (_Float16)pB0;
        pbuf[w][16 + g * 4 + e][16 + c] = (_Float16)pB1;
      }
      // wave-synchronous LDS (same wave wrote, same wave reads)
      half8 paA = *(const half8*)&pbuf[w][c][g * 8];
      half8 paB = *(const half8*)&pbuf[w][16 + c][g * 8];

      // attn stores: 4 instructions x 1 KB contiguous (8 rows x 128 B each)
#pragma unroll
      for (int s = 0; s < 4; s++) {
        const int r = (lane >> 3) + s * 8;
        const int c4 = (lane & 7) * 4;
        half4 h = *(const half4*)&pbuf[w][r][c4];
        f32x4 o;
#pragma unroll
        for (int j = 0; j < 4; j++) o[j] = (float)h[j];
        __builtin_nontemporal_store(o,
            (f32x4*)(attn_base + (size_t)r * S_LEN + kt * 32 + c4));
      }
      // PV: shared V fragments feed both row-tiles
#pragma unroll
      for (int nn = 0; nn < 4; nn++) {
        const _Float16* vp = Vb + (size_t)(nn * 16 + c) * S_LEN + kt * 32 + g * 8;
        half8 vb = *(const half8*)vp;
        ctxA[nn] = MFMA16x32(paA, vb, ctxA[nn]);
        ctxB[nn] = MFMA16x32(paB, vb, ctxB[nn]);
      }
    }
  }

  // ---------------- ctx combine across the two halves ----------------------
  __syncthreads();
  if (half == 1) {
#pragma unroll
    for (int nn = 0; nn < 4; nn++) {
#pragma unroll
      for (int e = 0; e < 4; e++) {
        cbuf[tb][g * 4 + e][nn * 16 + c] = ctxA[nn][e];
        cbuf[tb][16 + g * 4 + e][nn * 16 + c] = ctxB[nn][e];
      }
    }
  }
  __syncthreads();
  if (half == 0) {
    float* cb = out + ((size_t)(bh * S_LEN + q0)) * DKV;
#pragma unroll
    for (int nn = 0; nn < 4; nn++) {
#pragma unroll
      for (int e = 0; e < 4; e++) {
        float vA = ctxA[nn][e] + cbuf[tb][g * 4 + e][nn * 16 + c];
        float vB = ctxB[nn][e] + cbuf[tb][16 + g * 4 + e][nn * 16 + c];
        __builtin_nontemporal_store(vA, cb + (size_t)(g * 4 + e) * DKV + nn * 16 + c);
        __builtin_nontemporal_store(vB, cb + (size_t)(16 + g * 4 + e) * DKV + nn * 16 + c);
      }
    }
  }
}

// ---------------------------------------------------------------------------
// Fallback (R1 kernel) if ws is too small.
// ---------------------------------------------------------------------------
__global__ __launch_bounds__(512, 1)
void attn_slow_kernel(const float* __restrict__ Q, const float* __restrict__ K,
                      const float* __restrict__ V, const void* __restrict__ maskv,
                      float* __restrict__ out, const int* __restrict__ flag) {
  __shared__ __align__(16) unsigned char smem[16 * 2056 * 2];
  __shared__ float redm[8][16];
  __shared__ float reds[8][16];
  _Float16 (*P)[2056] = (_Float16 (*)[2056])smem;

  const int bh = blockIdx.y;
  const int q0 = blockIdx.x << 4;
  const int tid = threadIdx.x;
  const int w = tid >> 6;
  const int lane = tid & 63;
  const int g = lane >> 4;
  const int c = lane & 15;
  const int k0 = w << 8;

  const bool mask_w = (*flag) != 0;
  const unsigned char* m8 = (const unsigned char*)maskv;
  const unsigned int* m32 = (const unsigned int*)maskv;

  const float* Qb = Q + ((size_t)bh * S_LEN + q0) * DKV;
  const float* Kb = K + (size_t)bh * S_LEN * DKV;
  const float* Vb = V + (size_t)bh * S_LEN * DKV;
  const size_t mbase = ((size_t)bh * S_LEN + q0) * S_LEN;
  float* ctx_out = out + ((size_t)bh * S_LEN + q0) * DKV;
  float* attn_out = out + CTX_ELEMS + mbase;

  half8 a0, a1;
  {
    const float* qrow = Qb + (size_t)c * DKV + g * 8;
    f32x4 x0 = *(const f32x4*)(qrow);
    f32x4 x1 = *(const f32x4*)(qrow + 4);
    f32x4 y0 = *(const f32x4*)(qrow + 32);
    f32x4 y1 = *(const f32x4*)(qrow + 36);
#pragma unroll
    for (int j = 0; j < 4; j++) {
      a0[j] = (_Float16)x0[j]; a0[4 + j] = (_Float16)x1[j];
      a1[j] = (_Float16)y0[j]; a1[4 + j] = (_Float16)y1[j];
    }
  }

  f32x4 acc[16];
#pragma unroll
  for (int n = 0; n < 16; n++) acc[n] = (f32x4)0.0f;
#pragma unroll
  for (int n = 0; n < 16; n++) {
    const float* kr = Kb + (size_t)(k0 + n * 16 + c) * DKV + g * 8;
    f32x4 x0 = *(const f32x4*)(kr);
    f32x4 x1 = *(const f32x4*)(kr + 4);
    f32x4 y0 = *(const f32x4*)(kr + 32);
    f32x4 y1 = *(const f32x4*)(kr + 36);
    half8 b0, b1;
#pragma unroll
    for (int j = 0; j < 4; j++) {
      b0[j] = (_Float16)x0[j]; b0[4 + j] = (_Float16)x1[j];
      b1[j] = (_Float16)y0[j]; b1[4 + j] = (_Float16)y1[j];
    }
    acc[n] = MFMA16x32(a0, b0, acc[n]);
    acc[n] = MFMA16x32(a1, b1, acc[n]);
  }

  float mx[4] = {-1e9f, -1e9f, -1e9f, -1e9f};
#pragma unroll
  for (int n = 0; n < 16; n++) {
    const int kc = k0 + n * 16 + c;
#pragma unroll
    for (int e = 0; e < 4; e++) {
      const size_t mi = mbase + (size_t)(g * 4 + e) * S_LEN + kc;
      bool masked;
      if (mask_w) masked = (__builtin_nontemporal_load(&m32[mi]) != 0u);
      else        masked = (__builtin_nontemporal_load(&m8[mi]) != 0);
      float s = masked ? -1e9f : acc[n][e] * 0.125f;
      acc[n][e] = s;
      mx[e] = fmaxf(mx[e], s);
    }
  }
#pragma unroll
  for (int off = 1; off < 16; off <<= 1) {
#pragma unroll
    for (int e = 0; e < 4; e++)
      mx[e] = fmaxf(mx[e], __shfl_xor(mx[e], off, 64));
  }
  if (c == 0) {
#pragma unroll
    for (int e = 0; e < 4; e++) redm[w][g * 4 + e] = mx[e];
  }
  __syncthreads();
  float m[4], sm[4];
#pragma unroll
  for (int e = 0; e < 4; e++) {
    float v = redm[0][g * 4 + e];
#pragma unroll
    for (int ww = 1; ww < 8; ww++) v = fmaxf(v, redm[ww][g * 4 + e]);
    m[e] = v;
    sm[e] = 0.0f;
  }
#pragma unroll
  for (int n = 0; n < 16; n++) {
#pragma unroll
    for (int e = 0; e < 4; e++) {
      float p = __expf(acc[n][e] - m[e]);
      acc[n][e] = p;
      sm[e] += p;
    }
  }
#pragma unroll
  for (int off = 1; off < 16; off <<= 1) {
#pragma unroll
    for (int e = 0; e < 4; e++) sm[e] += __shfl_xor(sm[e], off, 64);
  }
  if (c == 0) {
#pragma unroll
    for (int e = 0; e < 4; e++) reds[w][g * 4 + e] = sm[e];
  }
  __syncthreads();
  float inv[4];
#pragma unroll
  for (int e = 0; e < 4; e++) {
    float z = 0.0f;
#pragma unroll
    for (int ww = 0; ww < 8; ww++) z += reds[ww][g * 4 + e];
    inv[e] = 1.0f / z;
  }
#pragma unroll
  for (int n = 0; n < 16; n++) {
    const int kc = k0 + n * 16 + c;
#pragma unroll
    for (int e = 0; e < 4; e++) {
      float v = acc[n][e] * inv[e];
      __builtin_nontemporal_store(v, &attn_out[(size_t)(g * 4 + e) * S_LEN + kc]);
      P[g * 4 + e][kc] = (_Float16)v;
    }
  }
  __syncthreads();

  f32x4 ctx[4];
#pragma unroll
  for (int n = 0; n < 4; n++) ctx[n] = (f32x4)0.0f;
  for (int ks = 0; ks < 8; ks++) {
    const int kb = k0 + ks * 32;
    half8 pa = *(const half8*)&P[c][kb + g * 8];
#pragma unroll
    for (int n = 0; n < 4; n++) {
      const float* vp = Vb + (size_t)(kb + g * 8) * DKV + n * 16 + c;
      half8 vb;
#pragma unroll
      for (int j = 0; j < 8; j++) vb[j] = (_Float16)vp[(size_t)j * DKV];
      ctx[n] = MFMA16x32(pa, vb, ctx[n]);
    }
  }
  __syncthreads();

  float* red2 = (float*)smem;
#pragma unroll
  for (int n = 0; n < 4; n++) {
#pragma unroll
    for (int e = 0; e < 4; e++)
      red2[((w * 16) + g * 4 + e) * 64 + n * 16 + c] = ctx[n][e];
  }
  __syncthreads();
  for (int i = tid; i < 16 * 64; i += 512) {
    int q = i >> 6, d = i & 63;
    float ssum = 0.0f;
#pragma unroll
    for (int ww = 0; ww < 8; ww++) ssum += red2[((ww * 16) + q) * 64 + d];
    ctx_out[(size_t)q * DKV + d] = ssum;
  }
}

extern "C" void kernel_launch(void* const* d_in, const int* in_sizes, int n_in,
                              void* d_out, int out_size, void* d_ws, size_t ws_size,
                              hipStream_t stream) {
  (void)in_sizes; (void)n_in; (void)out_size;
  const float* Q = (const float*)d_in[0];
  const float* K = (const float*)d_in[1];
  const float* V = (const float*)d_in[2];
  const void* mask = d_in[3];

  const size_t HBYTES = (size_t)NBH * S_LEN * DKV * sizeof(_Float16);       // 8 MB
  const size_t BITBYTES = (size_t)NBH * S_LEN * (S_LEN / 32) * 4;           // 16 MB
  const size_t NEED = 256 + 3 * HBYTES + BITBYTES;

  int* flag = (int*)d_ws;
  hipLaunchKernelGGL(detect_mask_kernel, dim3(1), dim3(256), 0, stream,
                     (const unsigned char*)mask, flag);

  if (ws_size >= NEED) {
    _Float16* QH = (_Float16*)((char*)d_ws + 256);
    _Float16* KH = (_Float16*)((char*)d_ws + 256 + HBYTES);
    _Float16* VT = (_Float16*)((char*)d_ws + 256 + 2 * HBYTES);
    unsigned int* bits = (unsigned int*)((char*)d_ws + 256 + 3 * HBYTES);
    const int n4 = NBH * S_LEN * DKV / 4;
    hipLaunchKernelGGL(pack_mask_kernel, dim3(2048), dim3(256), 0, stream,
                       mask, flag, bits);
    hipLaunchKernelGGL(convert_f32_f16_kernel, dim3(n4 / 256), dim3(256), 0, stream, Q, QH);
    hipLaunchKernelGGL(convert_f32_f16_kernel, dim3(n4 / 256), dim3(256), 0, stream, K, KH);
    hipLaunchKernelGGL(transpose_v_kernel, dim3(S_LEN / 64, NBH), dim3(256), 0, stream, V, VT);
    hipLaunchKernelGGL(attn_v7_kernel, dim3(512), dim3(512), 0, stream,
                       QH, KH, VT, bits, (float*)d_out);
  } else {
    hipLaunchKernelGGL(attn_slow_kernel, dim3(128, 32), dim3(512), 0, stream,
                       Q, K, V, mask, (float*)d_out, flag);
  }
}